// Round 20
// baseline (387.373 us; speedup 1.0000x reference)
//
#include <hip/hip_runtime.h>
#include <hip/hip_fp16.h>
#include <math.h>

// ---------------------------------------------------------------------------
// TacticalGAT round 20 (consolidation): (1) xr table stored fp16 (GEMM writes
// both outputs packed half: 50->25.6MB writes, gat xr reads 38->19MB, -2 cvt
// per node); (2) log2e folded into att -> exp2f (saves one v_mul per edge
// score).  Structure identical to r19 (383.0us best: 8-row GEMM tile, DPP
// reductions, self-loop-as-edge CSR, persistent oversubscribed gat waves).
// ---------------------------------------------------------------------------

union H2U { __half2 h; unsigned u; };
typedef _Float16 hv2_t __attribute__((ext_vector_type(2)));
typedef unsigned uv4_t __attribute__((ext_vector_type(4)));

__device__ __forceinline__ __half2 hmax2(__half2 a, __half2 b) {
  union { __half2 h; hv2_t v; } x, y, r;
  x.h = a; y.h = b;
  r.v = __builtin_elementwise_max(x.v, y.v);
  return r.h;
}

#if __has_builtin(__builtin_amdgcn_fdot2)
__device__ __forceinline__ float dot2f(__half2 a, __half2 b, float c) {
  union { __half2 h; hv2_t v; } x, y;
  x.h = a; y.h = b;
  return __builtin_amdgcn_fdot2(x.v, y.v, c, false);
}
#else
__device__ __forceinline__ float dot2f(__half2 a, __half2 b, float c) {
  float2 af = __half22float2(a), bf = __half22float2(b);
  return fmaf(af.x, bf.x, fmaf(af.y, bf.y, c));
}
#endif

// sum over the 16-lane DPP row (pure VALU).
#if __has_builtin(__builtin_amdgcn_update_dpp)
template <int CTRL>
__device__ __forceinline__ float dpp_add(float v) {
  int r = __builtin_amdgcn_update_dpp(0, __builtin_bit_cast(int, v),
                                      CTRL, 0xf, 0xf, true);
  return v + __builtin_bit_cast(float, r);
}
__device__ __forceinline__ float row_sum16(float v) {
  v = dpp_add<0x121>(v);  // row_ror:1
  v = dpp_add<0x122>(v);  // row_ror:2
  v = dpp_add<0x124>(v);  // row_ror:4
  v = dpp_add<0x128>(v);  // row_ror:8
  return v;
}
#else
__device__ __forceinline__ float row_sum16(float v) {
  v += __shfl_xor(v, 1);
  v += __shfl_xor(v, 2);
  v += __shfl_xor(v, 4);
  v += __shfl_xor(v, 8);
  return v;
}
#endif

__device__ __forceinline__ float lowf(unsigned u) {
  H2U t; t.u = u;
  return __half2float(__low2half(t.h));
}

#define LOG2E 1.44269504088896f

// ---------------- CSR build -------------------------------------------------
__global__ void hist_k(const int* __restrict__ dst, int* __restrict__ deg,
                       int* __restrict__ rank, int E) {
  int e = blockIdx.x * 256 + threadIdx.x;
  if (e < E) rank[e] = atomicAdd(&deg[dst[e]], 1);
}

__global__ void blocksum_k(const int* __restrict__ deg, int* __restrict__ bsum, int N) {
  __shared__ int s[256];
  int i = blockIdx.x * 256 + threadIdx.x;
  s[threadIdx.x] = (i < N) ? deg[i] : 0;
  __syncthreads();
  for (int off = 128; off; off >>= 1) {
    if (threadIdx.x < off) s[threadIdx.x] += s[threadIdx.x + off];
    __syncthreads();
  }
  if (threadIdx.x == 0) bsum[blockIdx.x] = s[0];
}

// rowptr over deg+1 slots per node (self-loop slot at rowptr[n+1]-1).
__global__ void writeptr_k(const int* __restrict__ deg, const int* __restrict__ bsum,
                           int* __restrict__ rowptr, int N, int E) {
  __shared__ int s[256];
  __shared__ int bs[256];
  int t = threadIdx.x;
  int i = blockIdx.x * 256 + t;
  bs[t] = (t < (int)blockIdx.x) ? bsum[t] : 0;
  s[t] = (i < N) ? deg[i] : 0;
  __syncthreads();
  for (int off = 128; off; off >>= 1) {
    if (t < off) bs[t] += bs[t + off];
    __syncthreads();
  }
  int base = bs[0];
  __syncthreads();
  for (int off = 1; off < 256; off <<= 1) {
    int v = (t >= off) ? s[t - off] : 0;
    __syncthreads();
    if (t >= off) s[t] += v;
    __syncthreads();
  }
  int excl = base + ((t == 0) ? 0 : s[t - 1]) + i;
  if (i < N) rowptr[i] = excl;
  if (i == N - 1) rowptr[N] = E + N;
}

// edge record: {src, splat(ea0), splat(ea1), splat(ea2)} = 16B; no atomics.
__global__ void fill_k(const int* __restrict__ src, const int* __restrict__ dst,
                       const float* __restrict__ eattr, const int* __restrict__ rowptr,
                       const int* __restrict__ rank, uint4* __restrict__ erec, int E) {
  int e = blockIdx.x * 256 + threadIdx.x;
  if (e >= E) return;
  int pos = rowptr[dst[e]] + rank[e];
  H2U a0, a1, a2;
  float e0 = eattr[e * 3 + 0], e1 = eattr[e * 3 + 1], e2 = eattr[e * 3 + 2];
  a0.h = __floats2half2_rn(e0, e0);
  a1.h = __floats2half2_rn(e1, e1);
  a2.h = __floats2half2_rn(e2, e2);
  uv4_t v = {(unsigned)src[e], a0.u, a1.u, a2.u};
  __builtin_nontemporal_store(v, (uv4_t*)&erec[pos]);
}

// wave per node: average the real edges' attrs, write self-loop record.
__global__ void loopattr_k(const int* __restrict__ rowptr, uint4* __restrict__ erec, int N) {
  int lane = threadIdx.x & 63;
  int n = (int)((blockIdx.x * 256 + threadIdx.x) >> 6);
  if (n >= N) return;
  int beg = rowptr[n], endr = rowptr[n + 1] - 1;  // real edges
  float f0 = 0.f, f1 = 0.f, f2 = 0.f;
  for (int i = beg + lane; i < endr; i += 64) {
    uint4 r = erec[i];
    f0 += lowf(r.y);
    f1 += lowf(r.z);
    f2 += lowf(r.w);
  }
#pragma unroll
  for (int off = 1; off < 64; off <<= 1) {
    f0 += __shfl_xor(f0, off);
    f1 += __shfl_xor(f1, off);
    f2 += __shfl_xor(f2, off);
  }
  if (lane == 0) {
    float inv = 1.0f / fmaxf((float)(endr - beg), 1.0f);
    H2U a0, a1, a2;
    a0.h = __floats2half2_rn(f0 * inv, f0 * inv);
    a1.h = __floats2half2_rn(f1 * inv, f1 * inv);
    a2.h = __floats2half2_rn(f2 * inv, f2 * inv);
    erec[endr] = make_uint4((unsigned)n, a0.u, a1.u, a2.u);
  }
}

// ---------------- fused dual node linear, dot2-f16, 8-row tile --------------
// Both outputs fp16 (gather table + xr table).
template <int J>
__global__ __launch_bounds__(256) void node_linear2t_k(
    const float* __restrict__ X,
    const float* __restrict__ W1, const float* __restrict__ b1v,
    const float* __restrict__ W2, const float* __restrict__ b2v,
    __half* __restrict__ out1, __half* __restrict__ out2, int nrows) {
  constexpr int K = 128, KB = 32;
  constexpr int JG = J / 4;
  constexpr int RG = 256 / JG;
  constexpr int RB = RG * 8;       // 8 rows per thread
  constexpr int XP2 = RB + 4;
  constexpr int WP2 = J + 4;
  __shared__ __align__(16) __half2 sXT2[K / 2][XP2];
  __shared__ __align__(16) __half2 sW1T2[KB / 2][WP2];
  __shared__ __align__(16) __half2 sW2T2[KB / 2][WP2];

  int tid = threadIdx.x;
  int n0 = blockIdx.x * RB;

  {  // stage X as k-pairs (transposed)
    int r = tid & (RB - 1);
    constexpr int KQSX = 256 / RB;
    int n = n0 + r;
    bool ok = n < nrows;
    for (int kq = tid / RB; kq < K / 4; kq += KQSX) {
      float4 v = ok ? *(const float4*)&X[(size_t)n * K + kq * 4]
                    : make_float4(0.f, 0.f, 0.f, 0.f);
      sXT2[kq * 2 + 0][r] = __floats2half2_rn(v.x, v.y);
      sXT2[kq * 2 + 1][r] = __floats2half2_rn(v.z, v.w);
    }
  }

  int jg = tid % JG;
  int rg = tid / JG;
  float acc1[8][4] = {}, acc2[8][4] = {};

  for (int kb = 0; kb < K / KB; ++kb) {
    __syncthreads();
    {  // stage W tile transposed
      int j = tid & (J - 1);
      constexpr int KQS = 256 / J;
      for (int kq = tid / J; kq < KB / 4; kq += KQS) {
        float4 v1 = *(const float4*)&W1[(size_t)j * K + kb * KB + kq * 4];
        float4 v2 = *(const float4*)&W2[(size_t)j * K + kb * KB + kq * 4];
        sW1T2[kq * 2 + 0][j] = __floats2half2_rn(v1.x, v1.y);
        sW1T2[kq * 2 + 1][j] = __floats2half2_rn(v1.z, v1.w);
        sW2T2[kq * 2 + 0][j] = __floats2half2_rn(v2.x, v2.y);
        sW2T2[kq * 2 + 1][j] = __floats2half2_rn(v2.z, v2.w);
      }
    }
    __syncthreads();
#pragma unroll
    for (int k2 = 0; k2 < KB / 2; ++k2) {
      __half2 xs2[8], w1s2[4], w2s2[4];
      *(float4*)&xs2[0] = *(const float4*)&sXT2[kb * (KB / 2) + k2][rg * 8];
      *(float4*)&xs2[4] = *(const float4*)&sXT2[kb * (KB / 2) + k2][rg * 8 + 4];
      *(float4*)w1s2 = *(const float4*)&sW1T2[k2][jg * 4];
      *(float4*)w2s2 = *(const float4*)&sW2T2[k2][jg * 4];
#pragma unroll
      for (int i = 0; i < 8; ++i)
#pragma unroll
        for (int q = 0; q < 4; ++q) {
          acc1[i][q] = dot2f(xs2[i], w1s2[q], acc1[i][q]);
          acc2[i][q] = dot2f(xs2[i], w2s2[q], acc2[i][q]);
        }
    }
  }

  float4 bv1 = *(const float4*)&b1v[jg * 4];
  float4 bv2 = *(const float4*)&b2v[jg * 4];
#pragma unroll
  for (int i = 0; i < 8; ++i) {
    int n = n0 + rg * 8 + i;
    if (n < nrows) {
      H2U a, b, c, d;
      a.h = __floats2half2_rn(acc1[i][0] + bv1.x, acc1[i][1] + bv1.y);
      b.h = __floats2half2_rn(acc1[i][2] + bv1.z, acc1[i][3] + bv1.w);
      *(uint2*)&out1[(size_t)n * J + jg * 4] = make_uint2(a.u, b.u);
      c.h = __floats2half2_rn(acc2[i][0] + bv2.x, acc2[i][1] + bv2.y);
      d.h = __floats2half2_rn(acc2[i][2] + bv2.z, acc2[i][3] + bv2.w);
      *(uint2*)&out2[(size_t)n * J + jg * 4] = make_uint2(c.u, d.u);
    }
  }
}

// ---------------- fused GATv2 layer 1 (H=4, C=32, concat) -------------------
__global__ __launch_bounds__(256) void gat1_fused_k(
    const int* __restrict__ rowptr, const uint4* __restrict__ erec,
    const __half* __restrict__ xlh, const __half* __restrict__ xrh,
    const float* __restrict__ We, const float* __restrict__ att,
    const float* __restrict__ bias, float* __restrict__ out, int N) {
  constexpr int CH = 8;
  int lane = threadIdx.x & 63;
  int wave0 = __builtin_amdgcn_readfirstlane(
      (int)((blockIdx.x * 256 + threadIdx.x) >> 6));
  int nwaves = gridDim.x * 4;
  const __half2* xl2p = (const __half2*)xlh;
  const __half2* xr2p = (const __half2*)xrh;
  int c0 = 2 * lane;
  __half2 w0p = __floats2half2_rn(We[c0 * 3 + 0], We[c0 * 3 + 3]);
  __half2 w1p = __floats2half2_rn(We[c0 * 3 + 1], We[c0 * 3 + 4]);
  __half2 w2p = __floats2half2_rn(We[c0 * 3 + 2], We[c0 * 3 + 5]);
  __half2 attp = __floats2half2_rn(att[c0] * LOG2E, att[c0 + 1] * LOG2E);
  __half2 k02 = __floats2half2_rn(0.2f, 0.2f);
  float2 bv = make_float2(bias[c0], bias[c0 + 1]);

  for (int n = wave0; n < N; n += nwaves) {
    __half2 xrp = xr2p[(size_t)n * 64 + lane];
    int beg = rowptr[n], end = rowptr[n + 1];
    int cnt = end - beg;  // deg + 1 (self-loop included)

    float acc0 = 0.f, acc1 = 0.f, den = 0.f;

    int nfull = cnt / CH;
    for (int ch = 0; ch < nfull; ++ch) {
      int b = beg + ch * CH;
      uint4 recs[CH];
#pragma unroll
      for (int j = 0; j < CH; ++j) recs[j] = erec[b + j];
      __half2 r_[CH];
#pragma unroll
      for (int j = 0; j < CH; ++j) {
        int s = __builtin_amdgcn_readfirstlane((int)recs[j].x);
        r_[j] = xl2p[(size_t)s * 64 + lane];
      }
#pragma unroll
      for (int j = 0; j < CH; ++j) {
        H2U e0, e1, e2;
        e0.u = recs[j].y; e1.u = recs[j].z; e2.u = recs[j].w;
        __half2 m = __hadd2(r_[j], xrp);
        m = __hfma2(e0.h, w0p, m);
        m = __hfma2(e1.h, w1p, m);
        m = __hfma2(e2.h, w2p, m);
        m = hmax2(m, __hmul2(m, k02));
        float v = row_sum16(dot2f(m, attp, 0.f));
        float ex = exp2f(v);
        float2 rfF = __half22float2(r_[j]);
        den += ex;
        acc0 = fmaf(ex, rfF.x, acc0);
        acc1 = fmaf(ex, rfF.y, acc1);
      }
    }
    // tail (guarded)
    {
      int b = beg + nfull * CH;
#pragma unroll
      for (int j = 0; j < CH; ++j) {
        int gi = b + j;
        bool valid = gi < end;
        uint4 rec = valid ? erec[gi] : make_uint4((unsigned)n, 0u, 0u, 0u);
        int s = __builtin_amdgcn_readfirstlane((int)rec.x);
        __half2 rf = xl2p[(size_t)s * 64 + lane];
        H2U e0, e1, e2;
        e0.u = rec.y; e1.u = rec.z; e2.u = rec.w;
        __half2 m = __hadd2(rf, xrp);
        m = __hfma2(e0.h, w0p, m);
        m = __hfma2(e1.h, w1p, m);
        m = __hfma2(e2.h, w2p, m);
        m = hmax2(m, __hmul2(m, k02));
        float v = row_sum16(dot2f(m, attp, 0.f));
        float ex = valid ? exp2f(v) : 0.f;
        float2 rfF = __half22float2(rf);
        den += ex;
        acc0 = fmaf(ex, rfF.x, acc0);
        acc1 = fmaf(ex, rfF.y, acc1);
      }
    }

    float o0 = acc0 / den + bv.x;
    float o1 = acc1 / den + bv.y;
    o0 = o0 > 0.f ? o0 : __expf(o0) - 1.0f;  // ELU
    o1 = o1 > 0.f ? o1 : __expf(o1) - 1.0f;
    *(float2*)&out[(size_t)n * 128 + c0] = make_float2(o0, o1);
  }
}

// ---------------- fused GATv2 layer 2 (H=1, C=64, mean) ---------------------
__global__ __launch_bounds__(256) void gat2_fused_k(
    const int* __restrict__ rowptr, const uint4* __restrict__ erec,
    const __half* __restrict__ xlh, const __half* __restrict__ xrh,
    const float* __restrict__ We, const float* __restrict__ att,
    const float* __restrict__ bias, float* __restrict__ out, int N) {
  constexpr int CP = 4;
  int lane = threadIdx.x & 63;
  int wave0 = __builtin_amdgcn_readfirstlane(
      (int)((blockIdx.x * 256 + threadIdx.x) >> 6));
  int nwaves = gridDim.x * 4;
  int sub = lane & 31, grp = lane >> 5;
  int c0 = 2 * sub;
  const __half2* xl2p = (const __half2*)xlh;  // row stride 32 half2
  const __half2* xr2p = (const __half2*)xrh;
  __half2 w0p = __floats2half2_rn(We[c0 * 3 + 0], We[c0 * 3 + 3]);
  __half2 w1p = __floats2half2_rn(We[c0 * 3 + 1], We[c0 * 3 + 4]);
  __half2 w2p = __floats2half2_rn(We[c0 * 3 + 2], We[c0 * 3 + 5]);
  __half2 attp = __floats2half2_rn(att[c0] * LOG2E, att[c0 + 1] * LOG2E);
  __half2 k02 = __floats2half2_rn(0.2f, 0.2f);
  float2 bv = make_float2(bias[c0], bias[c0 + 1]);

  for (int n = wave0; n < N; n += nwaves) {
    __half2 xrp = xr2p[(size_t)n * 32 + sub];
    int beg = rowptr[n], end = rowptr[n + 1];
    int cnt = end - beg;  // deg + 1

    float acc0 = 0.f, acc1 = 0.f, den = 0.f;

    int nfull = cnt / (2 * CP);
    int b = beg + grp;
    for (int ch = 0; ch < nfull; ++ch) {
      uint4 recs[CP];
      __half2 r_[CP];
#pragma unroll
      for (int j = 0; j < CP; ++j) recs[j] = erec[b + 2 * j];
#pragma unroll
      for (int j = 0; j < CP; ++j) r_[j] = xl2p[(size_t)recs[j].x * 32 + sub];
#pragma unroll
      for (int j = 0; j < CP; ++j) {
        H2U e0, e1, e2;
        e0.u = recs[j].y; e1.u = recs[j].z; e2.u = recs[j].w;
        __half2 m = __hadd2(r_[j], xrp);
        m = __hfma2(e0.h, w0p, m);
        m = __hfma2(e1.h, w1p, m);
        m = __hfma2(e2.h, w2p, m);
        m = hmax2(m, __hmul2(m, k02));
        float v = row_sum16(dot2f(m, attp, 0.f));
        v += __shfl_xor(v, 16);  // combine the two rows of this 32-lane group
        float ex = exp2f(v);
        float2 rfF = __half22float2(r_[j]);
        den += ex;
        acc0 = fmaf(ex, rfF.x, acc0);
        acc1 = fmaf(ex, rfF.y, acc1);
      }
      b += 2 * CP;
    }
    // tail (guarded)
    {
      int tb = beg + nfull * 2 * CP;
#pragma unroll
      for (int j = 0; j < CP; ++j) {
        int gi = tb + 2 * j + grp;
        bool valid = gi < end;
        uint4 rec = valid ? erec[gi] : make_uint4((unsigned)n, 0u, 0u, 0u);
        __half2 rf = xl2p[(size_t)rec.x * 32 + sub];
        H2U e0, e1, e2;
        e0.u = rec.y; e1.u = rec.z; e2.u = rec.w;
        __half2 m = __hadd2(rf, xrp);
        m = __hfma2(e0.h, w0p, m);
        m = __hfma2(e1.h, w1p, m);
        m = __hfma2(e2.h, w2p, m);
        m = hmax2(m, __hmul2(m, k02));
        float v = row_sum16(dot2f(m, attp, 0.f));
        v += __shfl_xor(v, 16);
        float ex = valid ? exp2f(v) : 0.f;
        float2 rfF = __half22float2(rf);
        den += ex;
        acc0 = fmaf(ex, rfF.x, acc0);
        acc1 = fmaf(ex, rfF.y, acc1);
      }
    }

    // combine the two edge groups
    acc0 += __shfl_xor(acc0, 32);
    acc1 += __shfl_xor(acc1, 32);
    den += __shfl_xor(den, 32);

    if (grp == 0) {
      float o0 = acc0 / den + bv.x;
      float o1 = acc1 / den + bv.y;
      o0 = o0 > 0.f ? o0 : __expf(o0) - 1.0f;  // ELU
      o1 = o1 > 0.f ? o1 : __expf(o1) - 1.0f;
      *(float2*)&out[(size_t)n * 64 + c0] = make_float2(o0, o1);
    }
  }
}

// ---------------- fused mean-pool + MLP head (block per graph, 256 thr) -----
__global__ void final_mlp_k(const float* __restrict__ h2, const int* __restrict__ batch,
                            int N, const float* __restrict__ u,
                            const float* __restrict__ W1, const float* __restrict__ b1,
                            const float* __restrict__ Wh, const float* __restrict__ bh,
                            float* __restrict__ out) {
  __shared__ float comb[4][64];
  __shared__ float feat[65];
  __shared__ float z[32];
  int g = blockIdx.x;
  int t = threadIdx.x;  // 256 threads
  int c = t & 63, q = t >> 6;
  int lo, hi;
  {
    int l = 0, h = N;
    while (l < h) { int m = (l + h) >> 1; if (batch[m] < g) l = m + 1; else h = m; }
    lo = l;
    h = N;
    while (l < h) { int m = (l + h) >> 1; if (batch[m] < g + 1) l = m + 1; else h = m; }
    hi = l;
  }
  float a = 0.f;
  for (int nn = lo + q; nn < hi; nn += 4) a += h2[(size_t)nn * 64 + c];
  comb[q][c] = a;
  __syncthreads();
  if (t < 64) {
    float s = comb[0][t] + comb[1][t] + comb[2][t] + comb[3][t];
    float inv = 1.0f / fmaxf((float)(hi - lo), 1.0f);
    feat[t] = s * inv;
    if (t == 0) feat[64] = u[g];
  }
  __syncthreads();
  if (t < 32) {
    float s = b1[t];
    for (int k = 0; k < 65; ++k) s += feat[k] * W1[t * 65 + k];
    z[t] = fmaxf(s, 0.0f);
  }
  __syncthreads();
  if (t < 10) {
    float s = bh[t];
    for (int k = 0; k < 32; ++k) s += z[k] * Wh[t * 32 + k];
    out[g * 10 + t] = s;
  }
}

// ---------------------------------------------------------------------------
extern "C" void kernel_launch(void* const* d_in, const int* in_sizes, int n_in,
                              void* d_out, int out_size, void* d_ws, size_t ws_size,
                              hipStream_t stream) {
  const float* x      = (const float*)d_in[0];
  const int*   eidx   = (const int*)d_in[1];
  const float* eattr  = (const float*)d_in[2];
  const int*   batch  = (const int*)d_in[3];
  const float* u      = (const float*)d_in[4];
  const float* Wl1    = (const float*)d_in[5];
  const float* bl1    = (const float*)d_in[6];
  const float* Wr1    = (const float*)d_in[7];
  const float* br1    = (const float*)d_in[8];
  const float* We1    = (const float*)d_in[9];
  const float* att1   = (const float*)d_in[10];
  const float* b1     = (const float*)d_in[11];
  const float* Wl2    = (const float*)d_in[12];
  const float* bl2    = (const float*)d_in[13];
  const float* Wr2    = (const float*)d_in[14];
  const float* br2    = (const float*)d_in[15];
  const float* We2    = (const float*)d_in[16];
  const float* att2   = (const float*)d_in[17];
  const float* b2     = (const float*)d_in[18];
  const float* W_lin1 = (const float*)d_in[19];
  const float* b_lin1 = (const float*)d_in[20];
  const float* W_head = (const float*)d_in[21];
  const float* b_head = (const float*)d_in[22];

  const int N = in_sizes[0] / 128;
  const int E = in_sizes[1] / 2;
  const int G = in_sizes[4];
  const int* srcp = eidx;
  const int* dstp = eidx + E;

  // ---- workspace layout ----
  __half* bufh = (__half*)d_ws;                     // xl half (N*128 -> N*64)
  __half* bufr = bufh + (size_t)N * 128;            // xr half (N*128 -> N*64)
  float* buf3 = (float*)(bufr + (size_t)N * 128);   // h1 (N*128) -> h2 (N*64)
  uint4* erec = (uint4*)(buf3 + (size_t)N * 128);   // E+N records (16B)
  int* rank   = (int*)(erec + ((size_t)E + N));     // E
  int* deg    = rank + E;                           // N
  int* rowptr = deg + N;                            // N+1
  int* bsum   = rowptr + N + 1;                     // 256

  const int nb = (N + 255) / 256;

  // ---- CSR build (sort edges by dst; slot deg+1 reserved per node) ----
  (void)hipMemsetAsync(deg, 0, sizeof(int) * (size_t)N, stream);
  hist_k<<<(E + 255) / 256, 256, 0, stream>>>(dstp, deg, rank, E);
  blocksum_k<<<nb, 256, 0, stream>>>(deg, bsum, N);
  writeptr_k<<<nb, 256, 0, stream>>>(deg, bsum, rowptr, N, E);
  fill_k<<<(E + 255) / 256, 256, 0, stream>>>(srcp, dstp, eattr, rowptr, rank, erec, E);
  loopattr_k<<<(N * 64 + 255) / 256, 256, 0, stream>>>(rowptr, erec, N);

  // ---- layer 1 (RB=64) ----
  node_linear2t_k<128><<<(N + 63) / 64, 256, 0, stream>>>(x, Wl1, bl1, Wr1, br1,
                                                          bufh, bufr, N);
  gat1_fused_k<<<8192, 256, 0, stream>>>(rowptr, erec, bufh, bufr,
                                         We1, att1, b1, buf3, N);

  // ---- layer 2 (RB=128) ----
  node_linear2t_k<64><<<(N + 127) / 128, 256, 0, stream>>>(buf3, Wl2, bl2, Wr2, br2,
                                                           bufh, bufr, N);
  gat2_fused_k<<<8192, 256, 0, stream>>>(rowptr, erec, bufh, bufr,
                                         We2, att2, b2, buf3, N);

  // ---- fused pool + head ----
  final_mlp_k<<<G, 256, 0, stream>>>(buf3, batch, N, u, W_lin1, b_lin1, W_head, b_head,
                                     (float*)d_out);
}

// Round 21
// 373.995 us; speedup vs baseline: 1.0358x; 1.0358x over previous
//
#include <hip/hip_runtime.h>
#include <hip/hip_fp16.h>
#include <math.h>

// ---------------------------------------------------------------------------
// TacticalGAT round 21: r20's exp2f lowered to the precise OCML routine
// (+~5 VALU/score -> gat1 60->66.8us).  Fixed: raw v_exp_f32 via
// __builtin_amdgcn_exp2f (1 inst, computes 2^x) with log2e still folded
// into att.  fp16 xr table kept (FETCH 110->102.6MB win).  Everything else
// identical to r19/r20 structure.
// ---------------------------------------------------------------------------

union H2U { __half2 h; unsigned u; };
typedef _Float16 hv2_t __attribute__((ext_vector_type(2)));
typedef unsigned uv4_t __attribute__((ext_vector_type(4)));

__device__ __forceinline__ __half2 hmax2(__half2 a, __half2 b) {
  union { __half2 h; hv2_t v; } x, y, r;
  x.h = a; y.h = b;
  r.v = __builtin_elementwise_max(x.v, y.v);
  return r.h;
}

#if __has_builtin(__builtin_amdgcn_fdot2)
__device__ __forceinline__ float dot2f(__half2 a, __half2 b, float c) {
  union { __half2 h; hv2_t v; } x, y;
  x.h = a; y.h = b;
  return __builtin_amdgcn_fdot2(x.v, y.v, c, false);
}
#else
__device__ __forceinline__ float dot2f(__half2 a, __half2 b, float c) {
  float2 af = __half22float2(a), bf = __half22float2(b);
  return fmaf(af.x, bf.x, fmaf(af.y, bf.y, c));
}
#endif

// raw v_exp_f32 (2^x, one instruction)
#if __has_builtin(__builtin_amdgcn_exp2f)
__device__ __forceinline__ float fexp2(float x) { return __builtin_amdgcn_exp2f(x); }
#else
__device__ __forceinline__ float fexp2(float x) { return exp2f(x); }
#endif

// sum over the 16-lane DPP row (pure VALU).
#if __has_builtin(__builtin_amdgcn_update_dpp)
template <int CTRL>
__device__ __forceinline__ float dpp_add(float v) {
  int r = __builtin_amdgcn_update_dpp(0, __builtin_bit_cast(int, v),
                                      CTRL, 0xf, 0xf, true);
  return v + __builtin_bit_cast(float, r);
}
__device__ __forceinline__ float row_sum16(float v) {
  v = dpp_add<0x121>(v);  // row_ror:1
  v = dpp_add<0x122>(v);  // row_ror:2
  v = dpp_add<0x124>(v);  // row_ror:4
  v = dpp_add<0x128>(v);  // row_ror:8
  return v;
}
#else
__device__ __forceinline__ float row_sum16(float v) {
  v += __shfl_xor(v, 1);
  v += __shfl_xor(v, 2);
  v += __shfl_xor(v, 4);
  v += __shfl_xor(v, 8);
  return v;
}
#endif

__device__ __forceinline__ float lowf(unsigned u) {
  H2U t; t.u = u;
  return __half2float(__low2half(t.h));
}

#define LOG2E 1.44269504088896f

// ---------------- CSR build -------------------------------------------------
__global__ void hist_k(const int* __restrict__ dst, int* __restrict__ deg,
                       int* __restrict__ rank, int E) {
  int e = blockIdx.x * 256 + threadIdx.x;
  if (e < E) rank[e] = atomicAdd(&deg[dst[e]], 1);
}

__global__ void blocksum_k(const int* __restrict__ deg, int* __restrict__ bsum, int N) {
  __shared__ int s[256];
  int i = blockIdx.x * 256 + threadIdx.x;
  s[threadIdx.x] = (i < N) ? deg[i] : 0;
  __syncthreads();
  for (int off = 128; off; off >>= 1) {
    if (threadIdx.x < off) s[threadIdx.x] += s[threadIdx.x + off];
    __syncthreads();
  }
  if (threadIdx.x == 0) bsum[blockIdx.x] = s[0];
}

// rowptr over deg+1 slots per node (self-loop slot at rowptr[n+1]-1).
__global__ void writeptr_k(const int* __restrict__ deg, const int* __restrict__ bsum,
                           int* __restrict__ rowptr, int N, int E) {
  __shared__ int s[256];
  __shared__ int bs[256];
  int t = threadIdx.x;
  int i = blockIdx.x * 256 + t;
  bs[t] = (t < (int)blockIdx.x) ? bsum[t] : 0;
  s[t] = (i < N) ? deg[i] : 0;
  __syncthreads();
  for (int off = 128; off; off >>= 1) {
    if (t < off) bs[t] += bs[t + off];
    __syncthreads();
  }
  int base = bs[0];
  __syncthreads();
  for (int off = 1; off < 256; off <<= 1) {
    int v = (t >= off) ? s[t - off] : 0;
    __syncthreads();
    if (t >= off) s[t] += v;
    __syncthreads();
  }
  int excl = base + ((t == 0) ? 0 : s[t - 1]) + i;
  if (i < N) rowptr[i] = excl;
  if (i == N - 1) rowptr[N] = E + N;
}

// edge record: {src, splat(ea0), splat(ea1), splat(ea2)} = 16B; no atomics.
__global__ void fill_k(const int* __restrict__ src, const int* __restrict__ dst,
                       const float* __restrict__ eattr, const int* __restrict__ rowptr,
                       const int* __restrict__ rank, uint4* __restrict__ erec, int E) {
  int e = blockIdx.x * 256 + threadIdx.x;
  if (e >= E) return;
  int pos = rowptr[dst[e]] + rank[e];
  H2U a0, a1, a2;
  float e0 = eattr[e * 3 + 0], e1 = eattr[e * 3 + 1], e2 = eattr[e * 3 + 2];
  a0.h = __floats2half2_rn(e0, e0);
  a1.h = __floats2half2_rn(e1, e1);
  a2.h = __floats2half2_rn(e2, e2);
  uv4_t v = {(unsigned)src[e], a0.u, a1.u, a2.u};
  __builtin_nontemporal_store(v, (uv4_t*)&erec[pos]);
}

// wave per node: average the real edges' attrs, write self-loop record.
__global__ void loopattr_k(const int* __restrict__ rowptr, uint4* __restrict__ erec, int N) {
  int lane = threadIdx.x & 63;
  int n = (int)((blockIdx.x * 256 + threadIdx.x) >> 6);
  if (n >= N) return;
  int beg = rowptr[n], endr = rowptr[n + 1] - 1;  // real edges
  float f0 = 0.f, f1 = 0.f, f2 = 0.f;
  for (int i = beg + lane; i < endr; i += 64) {
    uint4 r = erec[i];
    f0 += lowf(r.y);
    f1 += lowf(r.z);
    f2 += lowf(r.w);
  }
#pragma unroll
  for (int off = 1; off < 64; off <<= 1) {
    f0 += __shfl_xor(f0, off);
    f1 += __shfl_xor(f1, off);
    f2 += __shfl_xor(f2, off);
  }
  if (lane == 0) {
    float inv = 1.0f / fmaxf((float)(endr - beg), 1.0f);
    H2U a0, a1, a2;
    a0.h = __floats2half2_rn(f0 * inv, f0 * inv);
    a1.h = __floats2half2_rn(f1 * inv, f1 * inv);
    a2.h = __floats2half2_rn(f2 * inv, f2 * inv);
    erec[endr] = make_uint4((unsigned)n, a0.u, a1.u, a2.u);
  }
}

// ---------------- fused dual node linear, dot2-f16, 8-row tile --------------
// Both outputs fp16 (gather table + xr table).
template <int J>
__global__ __launch_bounds__(256) void node_linear2t_k(
    const float* __restrict__ X,
    const float* __restrict__ W1, const float* __restrict__ b1v,
    const float* __restrict__ W2, const float* __restrict__ b2v,
    __half* __restrict__ out1, __half* __restrict__ out2, int nrows) {
  constexpr int K = 128, KB = 32;
  constexpr int JG = J / 4;
  constexpr int RG = 256 / JG;
  constexpr int RB = RG * 8;       // 8 rows per thread
  constexpr int XP2 = RB + 4;
  constexpr int WP2 = J + 4;
  __shared__ __align__(16) __half2 sXT2[K / 2][XP2];
  __shared__ __align__(16) __half2 sW1T2[KB / 2][WP2];
  __shared__ __align__(16) __half2 sW2T2[KB / 2][WP2];

  int tid = threadIdx.x;
  int n0 = blockIdx.x * RB;

  {  // stage X as k-pairs (transposed)
    int r = tid & (RB - 1);
    constexpr int KQSX = 256 / RB;
    int n = n0 + r;
    bool ok = n < nrows;
    for (int kq = tid / RB; kq < K / 4; kq += KQSX) {
      float4 v = ok ? *(const float4*)&X[(size_t)n * K + kq * 4]
                    : make_float4(0.f, 0.f, 0.f, 0.f);
      sXT2[kq * 2 + 0][r] = __floats2half2_rn(v.x, v.y);
      sXT2[kq * 2 + 1][r] = __floats2half2_rn(v.z, v.w);
    }
  }

  int jg = tid % JG;
  int rg = tid / JG;
  float acc1[8][4] = {}, acc2[8][4] = {};

  for (int kb = 0; kb < K / KB; ++kb) {
    __syncthreads();
    {  // stage W tile transposed
      int j = tid & (J - 1);
      constexpr int KQS = 256 / J;
      for (int kq = tid / J; kq < KB / 4; kq += KQS) {
        float4 v1 = *(const float4*)&W1[(size_t)j * K + kb * KB + kq * 4];
        float4 v2 = *(const float4*)&W2[(size_t)j * K + kb * KB + kq * 4];
        sW1T2[kq * 2 + 0][j] = __floats2half2_rn(v1.x, v1.y);
        sW1T2[kq * 2 + 1][j] = __floats2half2_rn(v1.z, v1.w);
        sW2T2[kq * 2 + 0][j] = __floats2half2_rn(v2.x, v2.y);
        sW2T2[kq * 2 + 1][j] = __floats2half2_rn(v2.z, v2.w);
      }
    }
    __syncthreads();
#pragma unroll
    for (int k2 = 0; k2 < KB / 2; ++k2) {
      __half2 xs2[8], w1s2[4], w2s2[4];
      *(float4*)&xs2[0] = *(const float4*)&sXT2[kb * (KB / 2) + k2][rg * 8];
      *(float4*)&xs2[4] = *(const float4*)&sXT2[kb * (KB / 2) + k2][rg * 8 + 4];
      *(float4*)w1s2 = *(const float4*)&sW1T2[k2][jg * 4];
      *(float4*)w2s2 = *(const float4*)&sW2T2[k2][jg * 4];
#pragma unroll
      for (int i = 0; i < 8; ++i)
#pragma unroll
        for (int q = 0; q < 4; ++q) {
          acc1[i][q] = dot2f(xs2[i], w1s2[q], acc1[i][q]);
          acc2[i][q] = dot2f(xs2[i], w2s2[q], acc2[i][q]);
        }
    }
  }

  float4 bv1 = *(const float4*)&b1v[jg * 4];
  float4 bv2 = *(const float4*)&b2v[jg * 4];
#pragma unroll
  for (int i = 0; i < 8; ++i) {
    int n = n0 + rg * 8 + i;
    if (n < nrows) {
      H2U a, b, c, d;
      a.h = __floats2half2_rn(acc1[i][0] + bv1.x, acc1[i][1] + bv1.y);
      b.h = __floats2half2_rn(acc1[i][2] + bv1.z, acc1[i][3] + bv1.w);
      *(uint2*)&out1[(size_t)n * J + jg * 4] = make_uint2(a.u, b.u);
      c.h = __floats2half2_rn(acc2[i][0] + bv2.x, acc2[i][1] + bv2.y);
      d.h = __floats2half2_rn(acc2[i][2] + bv2.z, acc2[i][3] + bv2.w);
      *(uint2*)&out2[(size_t)n * J + jg * 4] = make_uint2(c.u, d.u);
    }
  }
}

// ---------------- fused GATv2 layer 1 (H=4, C=32, concat) -------------------
__global__ __launch_bounds__(256) void gat1_fused_k(
    const int* __restrict__ rowptr, const uint4* __restrict__ erec,
    const __half* __restrict__ xlh, const __half* __restrict__ xrh,
    const float* __restrict__ We, const float* __restrict__ att,
    const float* __restrict__ bias, float* __restrict__ out, int N) {
  constexpr int CH = 8;
  int lane = threadIdx.x & 63;
  int wave0 = __builtin_amdgcn_readfirstlane(
      (int)((blockIdx.x * 256 + threadIdx.x) >> 6));
  int nwaves = gridDim.x * 4;
  const __half2* xl2p = (const __half2*)xlh;
  const __half2* xr2p = (const __half2*)xrh;
  int c0 = 2 * lane;
  __half2 w0p = __floats2half2_rn(We[c0 * 3 + 0], We[c0 * 3 + 3]);
  __half2 w1p = __floats2half2_rn(We[c0 * 3 + 1], We[c0 * 3 + 4]);
  __half2 w2p = __floats2half2_rn(We[c0 * 3 + 2], We[c0 * 3 + 5]);
  __half2 attp = __floats2half2_rn(att[c0] * LOG2E, att[c0 + 1] * LOG2E);
  __half2 k02 = __floats2half2_rn(0.2f, 0.2f);
  float2 bv = make_float2(bias[c0], bias[c0 + 1]);

  for (int n = wave0; n < N; n += nwaves) {
    __half2 xrp = xr2p[(size_t)n * 64 + lane];
    int beg = rowptr[n], end = rowptr[n + 1];
    int cnt = end - beg;  // deg + 1 (self-loop included)

    float acc0 = 0.f, acc1 = 0.f, den = 0.f;

    int nfull = cnt / CH;
    for (int ch = 0; ch < nfull; ++ch) {
      int b = beg + ch * CH;
      uint4 recs[CH];
#pragma unroll
      for (int j = 0; j < CH; ++j) recs[j] = erec[b + j];
      __half2 r_[CH];
#pragma unroll
      for (int j = 0; j < CH; ++j) {
        int s = __builtin_amdgcn_readfirstlane((int)recs[j].x);
        r_[j] = xl2p[(size_t)s * 64 + lane];
      }
#pragma unroll
      for (int j = 0; j < CH; ++j) {
        H2U e0, e1, e2;
        e0.u = recs[j].y; e1.u = recs[j].z; e2.u = recs[j].w;
        __half2 m = __hadd2(r_[j], xrp);
        m = __hfma2(e0.h, w0p, m);
        m = __hfma2(e1.h, w1p, m);
        m = __hfma2(e2.h, w2p, m);
        m = hmax2(m, __hmul2(m, k02));
        float v = row_sum16(dot2f(m, attp, 0.f));
        float ex = fexp2(v);
        float2 rfF = __half22float2(r_[j]);
        den += ex;
        acc0 = fmaf(ex, rfF.x, acc0);
        acc1 = fmaf(ex, rfF.y, acc1);
      }
    }
    // tail (guarded)
    {
      int b = beg + nfull * CH;
#pragma unroll
      for (int j = 0; j < CH; ++j) {
        int gi = b + j;
        bool valid = gi < end;
        uint4 rec = valid ? erec[gi] : make_uint4((unsigned)n, 0u, 0u, 0u);
        int s = __builtin_amdgcn_readfirstlane((int)rec.x);
        __half2 rf = xl2p[(size_t)s * 64 + lane];
        H2U e0, e1, e2;
        e0.u = rec.y; e1.u = rec.z; e2.u = rec.w;
        __half2 m = __hadd2(rf, xrp);
        m = __hfma2(e0.h, w0p, m);
        m = __hfma2(e1.h, w1p, m);
        m = __hfma2(e2.h, w2p, m);
        m = hmax2(m, __hmul2(m, k02));
        float v = row_sum16(dot2f(m, attp, 0.f));
        float ex = valid ? fexp2(v) : 0.f;
        float2 rfF = __half22float2(rf);
        den += ex;
        acc0 = fmaf(ex, rfF.x, acc0);
        acc1 = fmaf(ex, rfF.y, acc1);
      }
    }

    float o0 = acc0 / den + bv.x;
    float o1 = acc1 / den + bv.y;
    o0 = o0 > 0.f ? o0 : __expf(o0) - 1.0f;  // ELU
    o1 = o1 > 0.f ? o1 : __expf(o1) - 1.0f;
    *(float2*)&out[(size_t)n * 128 + c0] = make_float2(o0, o1);
  }
}

// ---------------- fused GATv2 layer 2 (H=1, C=64, mean) ---------------------
__global__ __launch_bounds__(256) void gat2_fused_k(
    const int* __restrict__ rowptr, const uint4* __restrict__ erec,
    const __half* __restrict__ xlh, const __half* __restrict__ xrh,
    const float* __restrict__ We, const float* __restrict__ att,
    const float* __restrict__ bias, float* __restrict__ out, int N) {
  constexpr int CP = 4;
  int lane = threadIdx.x & 63;
  int wave0 = __builtin_amdgcn_readfirstlane(
      (int)((blockIdx.x * 256 + threadIdx.x) >> 6));
  int nwaves = gridDim.x * 4;
  int sub = lane & 31, grp = lane >> 5;
  int c0 = 2 * sub;
  const __half2* xl2p = (const __half2*)xlh;  // row stride 32 half2
  const __half2* xr2p = (const __half2*)xrh;
  __half2 w0p = __floats2half2_rn(We[c0 * 3 + 0], We[c0 * 3 + 3]);
  __half2 w1p = __floats2half2_rn(We[c0 * 3 + 1], We[c0 * 3 + 4]);
  __half2 w2p = __floats2half2_rn(We[c0 * 3 + 2], We[c0 * 3 + 5]);
  __half2 attp = __floats2half2_rn(att[c0] * LOG2E, att[c0 + 1] * LOG2E);
  __half2 k02 = __floats2half2_rn(0.2f, 0.2f);
  float2 bv = make_float2(bias[c0], bias[c0 + 1]);

  for (int n = wave0; n < N; n += nwaves) {
    __half2 xrp = xr2p[(size_t)n * 32 + sub];
    int beg = rowptr[n], end = rowptr[n + 1];
    int cnt = end - beg;  // deg + 1

    float acc0 = 0.f, acc1 = 0.f, den = 0.f;

    int nfull = cnt / (2 * CP);
    int b = beg + grp;
    for (int ch = 0; ch < nfull; ++ch) {
      uint4 recs[CP];
      __half2 r_[CP];
#pragma unroll
      for (int j = 0; j < CP; ++j) recs[j] = erec[b + 2 * j];
#pragma unroll
      for (int j = 0; j < CP; ++j) r_[j] = xl2p[(size_t)recs[j].x * 32 + sub];
#pragma unroll
      for (int j = 0; j < CP; ++j) {
        H2U e0, e1, e2;
        e0.u = recs[j].y; e1.u = recs[j].z; e2.u = recs[j].w;
        __half2 m = __hadd2(r_[j], xrp);
        m = __hfma2(e0.h, w0p, m);
        m = __hfma2(e1.h, w1p, m);
        m = __hfma2(e2.h, w2p, m);
        m = hmax2(m, __hmul2(m, k02));
        float v = row_sum16(dot2f(m, attp, 0.f));
        v += __shfl_xor(v, 16);  // combine the two rows of this 32-lane group
        float ex = fexp2(v);
        float2 rfF = __half22float2(r_[j]);
        den += ex;
        acc0 = fmaf(ex, rfF.x, acc0);
        acc1 = fmaf(ex, rfF.y, acc1);
      }
      b += 2 * CP;
    }
    // tail (guarded)
    {
      int tb = beg + nfull * 2 * CP;
#pragma unroll
      for (int j = 0; j < CP; ++j) {
        int gi = tb + 2 * j + grp;
        bool valid = gi < end;
        uint4 rec = valid ? erec[gi] : make_uint4((unsigned)n, 0u, 0u, 0u);
        __half2 rf = xl2p[(size_t)rec.x * 32 + sub];
        H2U e0, e1, e2;
        e0.u = rec.y; e1.u = rec.z; e2.u = rec.w;
        __half2 m = __hadd2(rf, xrp);
        m = __hfma2(e0.h, w0p, m);
        m = __hfma2(e1.h, w1p, m);
        m = __hfma2(e2.h, w2p, m);
        m = hmax2(m, __hmul2(m, k02));
        float v = row_sum16(dot2f(m, attp, 0.f));
        v += __shfl_xor(v, 16);
        float ex = valid ? fexp2(v) : 0.f;
        float2 rfF = __half22float2(rf);
        den += ex;
        acc0 = fmaf(ex, rfF.x, acc0);
        acc1 = fmaf(ex, rfF.y, acc1);
      }
    }

    // combine the two edge groups
    acc0 += __shfl_xor(acc0, 32);
    acc1 += __shfl_xor(acc1, 32);
    den += __shfl_xor(den, 32);

    if (grp == 0) {
      float o0 = acc0 / den + bv.x;
      float o1 = acc1 / den + bv.y;
      o0 = o0 > 0.f ? o0 : __expf(o0) - 1.0f;  // ELU
      o1 = o1 > 0.f ? o1 : __expf(o1) - 1.0f;
      *(float2*)&out[(size_t)n * 64 + c0] = make_float2(o0, o1);
    }
  }
}

// ---------------- fused mean-pool + MLP head (block per graph, 256 thr) -----
__global__ void final_mlp_k(const float* __restrict__ h2, const int* __restrict__ batch,
                            int N, const float* __restrict__ u,
                            const float* __restrict__ W1, const float* __restrict__ b1,
                            const float* __restrict__ Wh, const float* __restrict__ bh,
                            float* __restrict__ out) {
  __shared__ float comb[4][64];
  __shared__ float feat[65];
  __shared__ float z[32];
  int g = blockIdx.x;
  int t = threadIdx.x;  // 256 threads
  int c = t & 63, q = t >> 6;
  int lo, hi;
  {
    int l = 0, h = N;
    while (l < h) { int m = (l + h) >> 1; if (batch[m] < g) l = m + 1; else h = m; }
    lo = l;
    h = N;
    while (l < h) { int m = (l + h) >> 1; if (batch[m] < g + 1) l = m + 1; else h = m; }
    hi = l;
  }
  float a = 0.f;
  for (int nn = lo + q; nn < hi; nn += 4) a += h2[(size_t)nn * 64 + c];
  comb[q][c] = a;
  __syncthreads();
  if (t < 64) {
    float s = comb[0][t] + comb[1][t] + comb[2][t] + comb[3][t];
    float inv = 1.0f / fmaxf((float)(hi - lo), 1.0f);
    feat[t] = s * inv;
    if (t == 0) feat[64] = u[g];
  }
  __syncthreads();
  if (t < 32) {
    float s = b1[t];
    for (int k = 0; k < 65; ++k) s += feat[k] * W1[t * 65 + k];
    z[t] = fmaxf(s, 0.0f);
  }
  __syncthreads();
  if (t < 10) {
    float s = bh[t];
    for (int k = 0; k < 32; ++k) s += z[k] * Wh[t * 32 + k];
    out[g * 10 + t] = s;
  }
}

// ---------------------------------------------------------------------------
extern "C" void kernel_launch(void* const* d_in, const int* in_sizes, int n_in,
                              void* d_out, int out_size, void* d_ws, size_t ws_size,
                              hipStream_t stream) {
  const float* x      = (const float*)d_in[0];
  const int*   eidx   = (const int*)d_in[1];
  const float* eattr  = (const float*)d_in[2];
  const int*   batch  = (const int*)d_in[3];
  const float* u      = (const float*)d_in[4];
  const float* Wl1    = (const float*)d_in[5];
  const float* bl1    = (const float*)d_in[6];
  const float* Wr1    = (const float*)d_in[7];
  const float* br1    = (const float*)d_in[8];
  const float* We1    = (const float*)d_in[9];
  const float* att1   = (const float*)d_in[10];
  const float* b1     = (const float*)d_in[11];
  const float* Wl2    = (const float*)d_in[12];
  const float* bl2    = (const float*)d_in[13];
  const float* Wr2    = (const float*)d_in[14];
  const float* br2    = (const float*)d_in[15];
  const float* We2    = (const float*)d_in[16];
  const float* att2   = (const float*)d_in[17];
  const float* b2     = (const float*)d_in[18];
  const float* W_lin1 = (const float*)d_in[19];
  const float* b_lin1 = (const float*)d_in[20];
  const float* W_head = (const float*)d_in[21];
  const float* b_head = (const float*)d_in[22];

  const int N = in_sizes[0] / 128;
  const int E = in_sizes[1] / 2;
  const int G = in_sizes[4];
  const int* srcp = eidx;
  const int* dstp = eidx + E;

  // ---- workspace layout ----
  __half* bufh = (__half*)d_ws;                     // xl half (N*128 -> N*64)
  __half* bufr = bufh + (size_t)N * 128;            // xr half (N*128 -> N*64)
  float* buf3 = (float*)(bufr + (size_t)N * 128);   // h1 (N*128) -> h2 (N*64)
  uint4* erec = (uint4*)(buf3 + (size_t)N * 128);   // E+N records (16B)
  int* rank   = (int*)(erec + ((size_t)E + N));     // E
  int* deg    = rank + E;                           // N
  int* rowptr = deg + N;                            // N+1
  int* bsum   = rowptr + N + 1;                     // 256

  const int nb = (N + 255) / 256;

  // ---- CSR build (sort edges by dst; slot deg+1 reserved per node) ----
  (void)hipMemsetAsync(deg, 0, sizeof(int) * (size_t)N, stream);
  hist_k<<<(E + 255) / 256, 256, 0, stream>>>(dstp, deg, rank, E);
  blocksum_k<<<nb, 256, 0, stream>>>(deg, bsum, N);
  writeptr_k<<<nb, 256, 0, stream>>>(deg, bsum, rowptr, N, E);
  fill_k<<<(E + 255) / 256, 256, 0, stream>>>(srcp, dstp, eattr, rowptr, rank, erec, E);
  loopattr_k<<<(N * 64 + 255) / 256, 256, 0, stream>>>(rowptr, erec, N);

  // ---- layer 1 (RB=64) ----
  node_linear2t_k<128><<<(N + 63) / 64, 256, 0, stream>>>(x, Wl1, bl1, Wr1, br1,
                                                          bufh, bufr, N);
  gat1_fused_k<<<8192, 256, 0, stream>>>(rowptr, erec, bufh, bufr,
                                         We1, att1, b1, buf3, N);

  // ---- layer 2 (RB=128) ----
  node_linear2t_k<64><<<(N + 127) / 128, 256, 0, stream>>>(buf3, Wl2, bl2, Wr2, br2,
                                                           bufh, bufr, N);
  gat2_fused_k<<<8192, 256, 0, stream>>>(rowptr, erec, bufh, bufr,
                                         We2, att2, b2, buf3, N);

  // ---- fused pool + head ----
  final_mlp_k<<<G, 256, 0, stream>>>(buf3, batch, N, u, W_lin1, b_lin1, W_head, b_head,
                                     (float*)d_out);
}